// Round 7
// baseline (364.658 us; speedup 1.0000x reference)
//
#include <hip/hip_runtime.h>
#include <math.h>

#define Bn 32
#define Cn 256
#define Pn 1024                       // H*W tokens per batch
#define Tn (Bn * Pn * Cn)             // 8,388,608 elems per [b,p,c] tensor

typedef __bf16 bf16x8 __attribute__((ext_vector_type(8)));
typedef float  f32x4  __attribute__((ext_vector_type(4)));
typedef unsigned short u16;
typedef u16 u16x8 __attribute__((ext_vector_type(8)));

// ws layout in u16 units (total ~129 MiB):
#define XT1o ((size_t)0)              // xt of x1: [b][p][c] bf16
#define XT2o ((size_t)1 * Tn)         // xt of x2
#define Q1o  ((size_t)2 * Tn)         // q1 bf16 [b][p][c], pre-scaled 1/16
#define Ko   ((size_t)3 * Tn)         // k  bf16 [b][p][c]
#define VTo  ((size_t)4 * Tn)         // vt bf16 [b][c][p]
#define Q2o  ((size_t)5 * Tn)         // q2 bf16 [b][p][c], pre-scaled 1/16
#define H1o  ((size_t)6 * Tn)         // h1 bf16 [b][p][c]
#define H12o ((size_t)7 * Tn)         // h12 bf16 [b][p][c]
#define WBo  ((size_t)8 * Tn)         // 6 weight mats bf16 [o][c]: q1,k,v,q2,ps,pc

__device__ __forceinline__ u16 f2b(float f) {
    union { float f; unsigned u; } c; c.f = f;
    return (u16)((c.u + 0x7FFFu + ((c.u >> 16) & 1u)) >> 16);
}

// ---------------------------------------------------------------------------
// cvt: x1,x2 [b][c][p] fp32 -> xt [b][p][c] bf16 ; weights fp32 -> bf16.
// grid (16, 4, 70); block 256.
// ---------------------------------------------------------------------------
__global__ __launch_bounds__(256) void cvt_kernel(
    const float* __restrict__ x1, const float* __restrict__ x2,
    const float* __restrict__ wq1, const float* __restrict__ wk,
    const float* __restrict__ wv,  const float* __restrict__ wq2,
    const float* __restrict__ wps, const float* __restrict__ wpc,
    u16* __restrict__ ws16)
{
    const int z = blockIdx.z;
    const int tid = threadIdx.x;
    if (z >= 64) {
        const int widx = z - 64;
        const float* w = widx == 0 ? wq1 : widx == 1 ? wk : widx == 2 ? wv
                       : widx == 3 ? wq2 : widx == 4 ? wps : wpc;
        const int linear = blockIdx.x + 16 * blockIdx.y;   // 0..63
        const int e = linear * 1024 + tid * 4;
        float4 v = *(const float4*)&w[e];
        ushort4 o = make_ushort4(f2b(v.x), f2b(v.y), f2b(v.z), f2b(v.w));
        *(ushort4*)&ws16[WBo + (size_t)widx * 65536 + e] = o;
        return;
    }
    const int which = z >> 5, b = z & 31;
    const float* x = which ? x2 : x1;
    u16* xt = ws16 + (which ? XT2o : XT1o);
    const int p0 = blockIdx.x * 64, c0 = blockIdx.y * 64;
    __shared__ __align__(16) u16 T[64][80];
    #pragma unroll
    for (int i = 0; i < 4; i++) {
        int e = tid + i * 256;
        int c = e >> 4, p4 = e & 15;
        float4 v = *(const float4*)&x[((size_t)(b * Cn + c0 + c)) * Pn + p0 + p4 * 4];
        T[p4 * 4 + 0][c] = f2b(v.x);
        T[p4 * 4 + 1][c] = f2b(v.y);
        T[p4 * 4 + 2][c] = f2b(v.z);
        T[p4 * 4 + 3][c] = f2b(v.w);
    }
    __syncthreads();
    #pragma unroll
    for (int i = 0; i < 2; i++) {
        int e = tid + i * 256;
        int p = e >> 3, c8 = e & 7;
        u16x8 vv = *(const u16x8*)&T[p][c8 * 8];
        *(u16x8*)&xt[((size_t)(b * Pn + p0 + p)) * Cn + c0 + c8 * 8] = vv;
    }
}

// ---------------------------------------------------------------------------
// Shared 128x128x256 MFMA GEMM core, register-prefetch pipeline.
// ---------------------------------------------------------------------------
__device__ __forceinline__ void gemm_core(
    const u16* __restrict__ Ab, const u16* __restrict__ Bb,
    u16* __restrict__ As, u16* __restrict__ Bs, f32x4 acc[16], int tid)
{
    const int wv = tid >> 6, lane = tid & 63;
    const int ln = lane & 15, quad = lane >> 4;
    const int wr = wv >> 1, wc = wv & 1;
    const int srow = tid >> 3, sch = tid & 7;    // staging role
    const int pos = sch ^ (srow & 7);            // (srow+32i)&7 == srow&7

    u16x8 apre[4], bpre[4];
    #pragma unroll
    for (int i = 0; i < 4; i++) {
        int r = srow + 32 * i;
        apre[i] = *(const u16x8*)&Ab[(size_t)r * 256 + sch * 8];
        bpre[i] = *(const u16x8*)&Bb[(size_t)r * 256 + sch * 8];
    }

    for (int k0 = 0; k0 < 256; k0 += 64) {
        __syncthreads();
        #pragma unroll
        for (int i = 0; i < 4; i++) {
            int r = srow + 32 * i;
            *(u16x8*)&As[r * 64 + pos * 8] = apre[i];
            *(u16x8*)&Bs[r * 64 + pos * 8] = bpre[i];
        }
        __syncthreads();
        if (k0 < 192) {
            #pragma unroll
            for (int i = 0; i < 4; i++) {
                int r = srow + 32 * i;
                apre[i] = *(const u16x8*)&Ab[(size_t)r * 256 + (k0 + 64) + sch * 8];
                bpre[i] = *(const u16x8*)&Bb[(size_t)r * 256 + (k0 + 64) + sch * 8];
            }
        }
        bf16x8 af[4][2], bf[4][2];
        #pragma unroll
        for (int i = 0; i < 4; i++) {
            int row = wr * 64 + i * 16 + ln;
            #pragma unroll
            for (int kc = 0; kc < 2; kc++) {
                int p = (kc * 4 + quad) ^ (row & 7);
                af[i][kc] = *(const bf16x8*)&As[row * 64 + p * 8];
            }
        }
        #pragma unroll
        for (int j = 0; j < 4; j++) {
            int row = wc * 64 + j * 16 + ln;
            #pragma unroll
            for (int kc = 0; kc < 2; kc++) {
                int p = (kc * 4 + quad) ^ (row & 7);
                bf[j][kc] = *(const bf16x8*)&Bs[row * 64 + p * 8];
            }
        }
        #pragma unroll
        for (int kc = 0; kc < 2; kc++)
            #pragma unroll
            for (int i = 0; i < 4; i++)
                #pragma unroll
                for (int j = 0; j < 4; j++)
                    acc[i * 4 + j] = __builtin_amdgcn_mfma_f32_16x16x32_bf16(
                        af[i][kc], bf[j][kc], acc[i * 4 + j], 0, 0, 0);
    }
}

// ---------------------------------------------------------------------------
// proj: q1/k/q2 (mat 0,1,2): [32768 x 256] = xt . W^T ; V (mat 3): vt = W . xt^T
// grid (512, 4); block 256
// ---------------------------------------------------------------------------
__global__ __launch_bounds__(256) void proj_kernel(
    u16* __restrict__ ws16,
    const float* __restrict__ bq1, const float* __restrict__ bk,
    const float* __restrict__ bq2, const float* __restrict__ bv)
{
    __shared__ __align__(16) u16 As[128 * 64];
    __shared__ __align__(16) u16 Bs[128 * 64];
    const int tid = threadIdx.x;
    const int mat = blockIdx.y;
    const int wv = tid >> 6, lane = tid & 63;
    const int ln = lane & 15, quad = lane >> 4;
    const int wr = wv >> 1, wc = wv & 1;

    f32x4 acc[16];
    #pragma unroll
    for (int t = 0; t < 16; t++) acc[t] = (f32x4){0.f, 0.f, 0.f, 0.f};

    if (mat < 3) {
        const int m_tile = blockIdx.x >> 1, n_tile = blockIdx.x & 1;
        const size_t xtoff = (mat == 2) ? XT2o : XT1o;
        const int widx = (mat == 0) ? 0 : (mat == 1) ? 1 : 3;
        const float* bias = (mat == 0) ? bq1 : (mat == 1) ? bk : bq2;
        const float scale = (mat == 1) ? 1.0f : 0.0625f;
        u16* out = ws16 + ((mat == 0) ? Q1o : (mat == 1) ? Ko : Q2o);

        const u16* Ab = ws16 + xtoff + (size_t)m_tile * 128 * 256;
        const u16* Bb = ws16 + WBo + (size_t)widx * 65536 + (size_t)n_tile * 128 * 256;
        gemm_core(Ab, Bb, As, Bs, acc, tid);

        const int m0 = m_tile * 128;
        #pragma unroll
        for (int j = 0; j < 4; j++) {
            const int ncol = n_tile * 128 + wc * 64 + j * 16 + ln;
            const float bj = bias[ncol];
            #pragma unroll
            for (int i = 0; i < 4; i++) {
                const int mr = m0 + wr * 64 + i * 16 + quad * 4;
                #pragma unroll
                for (int r = 0; r < 4; r++)
                    out[(size_t)(mr + r) * 256 + ncol] =
                        f2b((acc[i * 4 + j][r] + bj) * scale);
            }
        }
    } else {
        const int b = blockIdx.x >> 4;
        const int o_tile = (blockIdx.x >> 3) & 1;
        const int p_tile = blockIdx.x & 7;
        const u16* Ab = ws16 + WBo + (size_t)2 * 65536 + (size_t)o_tile * 128 * 256;
        const u16* Bb = ws16 + XT1o + ((size_t)b * Pn + p_tile * 128) * 256;
        gemm_core(Ab, Bb, As, Bs, acc, tid);

        u16* vt = ws16 + VTo + (size_t)b * Cn * Pn;
        #pragma unroll
        for (int i = 0; i < 4; i++) {
            #pragma unroll
            for (int r = 0; r < 4; r++) {
                const int orow = o_tile * 128 + wr * 64 + i * 16 + quad * 4 + r;
                const float bo = bv[orow];
                #pragma unroll
                for (int j = 0; j < 4; j++) {
                    const int pcol = p_tile * 128 + wc * 64 + j * 16 + ln;
                    vt[(size_t)orow * Pn + pcol] = f2b(acc[i * 4 + j][r] + bo);
                }
            }
        }
    }
}

// ---------------------------------------------------------------------------
// attn v4: in-wave dual path + TRANSPOSED scores (S^T = mfma(kb, qa)).
// Lane holds 4 consecutive tokens per q-row (q=ln) -> P written as packed
// b64 instead of 16 scalar b16 writes; Plds layout [q][tok] feeds the PV
// A-fragment with the exact same read addresses as before.
// block = 4 waves = 64 q-rows; 32 k-tokens per iter. grid (16, 32).
// ---------------------------------------------------------------------------
__global__ __launch_bounds__(256, 2) void attn_kernel(u16* __restrict__ ws16)
{
    const u16* Q1 = ws16 + Q1o;
    const u16* Kg = ws16 + Ko;
    const u16* Vt = ws16 + VTo;
    const u16* Q2 = ws16 + Q2o;

    __shared__ __align__(16) u16 Klds[32 * 256];    // [tok][c], chunk swizzle ^ (tok&7)
    __shared__ __align__(16) u16 Vtlds[256 * 32];   // [c][tok], chunk swizzle ^ (c&3)
    __shared__ __align__(16) u16 Plds[4 * 2 * 16 * 40];  // per-wave P1/P12 [q][tok], pad 40

    const int b    = blockIdx.y;
    const int q0   = blockIdx.x * 64;
    const int tid  = threadIdx.x;
    const int wid  = tid >> 6;
    const int lane = tid & 63;
    const int ln   = lane & 15;
    const int quad = lane >> 4;
    u16* Pw = Plds + wid * (2 * 16 * 40);

    const size_t qrow = (size_t)(b * Pn + q0 + wid * 16 + ln) * Cn;
    bf16x8 qa1[8], qa2[8];
    #pragma unroll
    for (int ch = 0; ch < 8; ch++) {
        qa1[ch] = *(const bf16x8*)&Q1[qrow + ch * 32 + quad * 8];
        qa2[ch] = *(const bf16x8*)&Q2[qrow + ch * 32 + quad * 8];
    }

    f32x4 acc1[16], acc12[16];
    #pragma unroll
    for (int t = 0; t < 16; t++) {
        acc1[t] = (f32x4){0.f, 0.f, 0.f, 0.f};
        acc12[t] = (f32x4){0.f, 0.f, 0.f, 0.f};
    }
    float lp1 = 0.f, lp12 = 0.f;     // per-lane partials for q = ln

    const int tokK = tid >> 3, giK = tid & 7;
    const int cbV = tid >> 2, gvV = tid & 3;
    u16x8 kpre[4], vpre[4];

    {
        const size_t growK = (size_t)(b * Pn + 0 + tokK) * Cn;
        #pragma unroll
        for (int i = 0; i < 4; i++)
            kpre[i] = *(const u16x8*)&Kg[growK + (size_t)(8 * i + (giK ^ (tokK & 7))) * 8];
        #pragma unroll
        for (int i = 0; i < 4; i++) {
            int cl = cbV + 64 * i;
            vpre[i] = *(const u16x8*)&Vt[((size_t)(b * Cn + cl)) * Pn + 0 + gvV * 8];
        }
    }

    for (int kt = 0; kt < 32; kt++) {
        __syncthreads();   // (A) all waves done reading LDS of prev iter

        #pragma unroll
        for (int i = 0; i < 4; i++)
            *(u16x8*)&Klds[tokK * 256 + (8 * i + giK) * 8] = kpre[i];
        #pragma unroll
        for (int i = 0; i < 4; i++) {
            int cl = cbV + 64 * i;
            int gp = gvV ^ (cl & 3);
            *(u16x8*)&Vtlds[cl * 32 + gp * 8] = vpre[i];
        }
        __syncthreads();   // (B) tile visible

        if (kt < 31) {
            const int k0n = (kt + 1) * 32;
            const size_t growK = (size_t)(b * Pn + k0n + tokK) * Cn;
            #pragma unroll
            for (int i = 0; i < 4; i++)
                kpre[i] = *(const u16x8*)&Kg[growK + (size_t)(8 * i + (giK ^ (tokK & 7))) * 8];
            #pragma unroll
            for (int i = 0; i < 4; i++) {
                int cl = cbV + 64 * i;
                vpre[i] = *(const u16x8*)&Vt[((size_t)(b * Cn + cl)) * Pn + k0n + gvV * 8];
            }
        }

        // scores, TRANSPOSED: S^T = mfma(A=kb, B=qa) -> row = token, col = q
        float s1v[2][4], s2v[2][4];
        #pragma unroll
        for (int st = 0; st < 2; st++) {
            f32x4 s1 = (f32x4){0.f, 0.f, 0.f, 0.f};
            f32x4 s2 = (f32x4){0.f, 0.f, 0.f, 0.f};
            #pragma unroll
            for (int ch = 0; ch < 8; ch++) {
                bf16x8 kb = *(const bf16x8*)
                    &Klds[(st * 16 + ln) * 256 + (((ch * 4 + quad) ^ (ln & 7))) * 8];
                s1 = __builtin_amdgcn_mfma_f32_16x16x32_bf16(kb, qa1[ch], s1, 0, 0, 0);
                s2 = __builtin_amdgcn_mfma_f32_16x16x32_bf16(kb, qa2[ch], s2, 0, 0, 0);
            }
            #pragma unroll
            for (int r = 0; r < 4; r++) { s1v[st][r] = s1[r]; s2v[st][r] = s2[r]; }
        }

        // exp + packed P writes: lane holds tokens st*16+quad*4+{0..3} of row q=ln
        #pragma unroll
        for (int st = 0; st < 2; st++) {
            ushort4 w1, w12;
            float p1, p12;
            p1 = __expf(s1v[st][0]); p12 = p1 * __expf(s2v[st][0]);
            lp1 += p1; lp12 += p12; w1.x = f2b(p1); w12.x = f2b(p12);
            p1 = __expf(s1v[st][1]); p12 = p1 * __expf(s2v[st][1]);
            lp1 += p1; lp12 += p12; w1.y = f2b(p1); w12.y = f2b(p12);
            p1 = __expf(s1v[st][2]); p12 = p1 * __expf(s2v[st][2]);
            lp1 += p1; lp12 += p12; w1.z = f2b(p1); w12.z = f2b(p12);
            p1 = __expf(s1v[st][3]); p12 = p1 * __expf(s2v[st][3]);
            lp1 += p1; lp12 += p12; w1.w = f2b(p1); w12.w = f2b(p12);
            *(ushort4*)&Pw[ln * 40 + st * 16 + quad * 4]           = w1;
            *(ushort4*)&Pw[16 * 40 + ln * 40 + st * 16 + quad * 4] = w12;
        }

        // PV: pa reads identical addresses to before ([q][tok] layout)
        bf16x8 pa1 = *(const bf16x8*)&Pw[ln * 40 + quad * 8];
        bf16x8 pa2 = *(const bf16x8*)&Pw[16 * 40 + ln * 40 + quad * 8];
        #pragma unroll
        for (int t = 0; t < 16; t++) {
            bf16x8 vb = *(const bf16x8*)
                &Vtlds[(t * 16 + ln) * 32 + (quad ^ (ln & 3)) * 8];
            acc1[t]  = __builtin_amdgcn_mfma_f32_16x16x32_bf16(pa1, vb, acc1[t], 0, 0, 0);
            acc12[t] = __builtin_amdgcn_mfma_f32_16x16x32_bf16(pa2, vb, acc12[t], 0, 0, 0);
        }
    }

    // epilogue: l lives per-lane (q=ln); reduce across quads, broadcast per row
    lp1 += __shfl_xor(lp1, 16);  lp1 += __shfl_xor(lp1, 32);
    lp12 += __shfl_xor(lp12, 16); lp12 += __shfl_xor(lp12, 32);

    u16* H1 = ws16 + H1o;
    u16* H12 = ws16 + H12o;
    #pragma unroll
    for (int r = 0; r < 4; r++) {
        float i1 = 1.f / __shfl(lp1, quad * 4 + r);
        float i2 = 1.f / __shfl(lp12, quad * 4 + r);
        size_t rowb = (size_t)(b * Pn + q0 + wid * 16 + quad * 4 + r) * Cn;
        #pragma unroll
        for (int t = 0; t < 16; t++) {
            H1[rowb + t * 16 + ln]  = f2b(acc1[t][r] * i1);
            H12[rowb + t * 16 + ln] = f2b(acc12[t][r] * i2);
        }
    }
}

// ---------------------------------------------------------------------------
// outproj: out[mat][b][o][p] = x1[b][o][p] + bias[o] + sum_c h[b][p][c]*w[o][c]
// grid (16, 64); block 256
// ---------------------------------------------------------------------------
__global__ __launch_bounds__(256) void outproj_kernel(
    const float* __restrict__ x1,
    const float* __restrict__ bps, const float* __restrict__ bpc,
    const u16* __restrict__ ws16, float* __restrict__ outp)
{
    __shared__ __align__(16) u16 As[128 * 64];
    __shared__ __align__(16) u16 Bs[128 * 64];
    const int tid = threadIdx.x;
    const int o_tile = blockIdx.x >> 3, p_tile = blockIdx.x & 7;
    const int mat = blockIdx.y >> 5, b = blockIdx.y & 31;
    const int wv = tid >> 6, lane = tid & 63;
    const int ln = lane & 15, quad = lane >> 4;
    const int wr = wv >> 1, wc = wv & 1;

    f32x4 acc[16];
    #pragma unroll
    for (int t = 0; t < 16; t++) acc[t] = (f32x4){0.f, 0.f, 0.f, 0.f};

    const u16* Ab = ws16 + WBo + (size_t)(4 + mat) * 65536 + (size_t)o_tile * 128 * 256;
    const u16* Bb = ws16 + (mat ? H12o : H1o) + ((size_t)b * Pn + p_tile * 128) * 256;
    gemm_core(Ab, Bb, As, Bs, acc, tid);

    const float* bias = mat ? bpc : bps;
    float* out = outp + (size_t)mat * Tn;
    #pragma unroll
    for (int i = 0; i < 4; i++) {
        #pragma unroll
        for (int r = 0; r < 4; r++) {
            const int orow = o_tile * 128 + wr * 64 + i * 16 + quad * 4 + r;
            const float bo = bias[orow];
            #pragma unroll
            for (int j = 0; j < 4; j++) {
                const int pcol = p_tile * 128 + wc * 64 + j * 16 + ln;
                const size_t idx = ((size_t)b * Cn + orow) * Pn + pcol;
                out[idx] = x1[idx] + bo + acc[i * 4 + j][r];
            }
        }
    }
}

// ---------------------------------------------------------------------------
extern "C" void kernel_launch(void* const* d_in, const int* in_sizes, int n_in,
                              void* d_out, int out_size, void* d_ws, size_t ws_size,
                              hipStream_t stream)
{
    const float* x1  = (const float*)d_in[0];
    const float* x2  = (const float*)d_in[1];
    const float* wq1 = (const float*)d_in[2];
    const float* bq1 = (const float*)d_in[3];
    const float* wk  = (const float*)d_in[4];
    const float* bk  = (const float*)d_in[5];
    const float* wv  = (const float*)d_in[6];
    const float* bv  = (const float*)d_in[7];
    const float* wq2 = (const float*)d_in[8];
    const float* bq2 = (const float*)d_in[9];
    const float* wps = (const float*)d_in[10];
    const float* bps = (const float*)d_in[11];
    const float* wpc = (const float*)d_in[12];
    const float* bpc = (const float*)d_in[13];
    float* out = (float*)d_out;
    u16* ws16 = (u16*)d_ws;

    cvt_kernel<<<dim3(16, 4, 70), 256, 0, stream>>>(
        x1, x2, wq1, wk, wv, wq2, wps, wpc, ws16);
    proj_kernel<<<dim3(512, 4), 256, 0, stream>>>(ws16, bq1, bk, bq2, bv);
    attn_kernel<<<dim3(Pn / 64, Bn), 256, 0, stream>>>(ws16);
    outproj_kernel<<<dim3(16, 64), 256, 0, stream>>>(x1, bps, bpc, ws16, out);
}